// Round 2
// baseline (739.132 us; speedup 1.0000x reference)
//
#include <hip/hip_runtime.h>

static constexpr int BLK = 256;

__global__ void k_deg_init(float* __restrict__ deg, int n) {
    int i = blockIdx.x * BLK + threadIdx.x;
    if (i < n) deg[i] = 1.0f;  // self-loop
}

__global__ void k_deg_count(const int* __restrict__ dst, float* __restrict__ deg, int e) {
    int i = blockIdx.x * BLK + threadIdx.x;
    if (i < e) atomicAdd(&deg[dst[i]], 1.0f);
}

__global__ void k_deg_rsqrt(float* __restrict__ deg, int n) {
    int i = blockIdx.x * BLK + threadIdx.x;
    if (i < n) deg[i] = rsqrtf(deg[i]);  // deg >= 1 always (self-loop)
}

// out[n,COUT] = (RELU_IN? relu(in):in)[n,CIN] @ W[CIN,COUT]  (+b) (+relu)
template <int CIN, int COUT, bool RELU_IN, bool BIAS, bool RELU_OUT>
__global__ void k_transform(const float* __restrict__ in, const float* __restrict__ W,
                            const float* __restrict__ b, float* __restrict__ out, int n) {
    int t = blockIdx.x * BLK + threadIdx.x;
    int node = t / COUT, c = t % COUT;
    if (node >= n) return;
    const float* row = in + (size_t)node * CIN;
    float acc = BIAS ? b[c] : 0.0f;
#pragma unroll
    for (int k = 0; k < CIN; ++k) {
        float v = row[k];
        if (RELU_IN) v = fmaxf(v, 0.0f);
        acc = fmaf(v, W[k * COUT + c], acc);
    }
    if (RELU_OUT) acc = fmaxf(acc, 0.0f);
    out[t] = acc;
}

// agg[n,C] = (BIAS? b[c]:0) + (RELU_IN? relu(h):h)[n,C] * dis[n]^2   (self-loop term)
template <int C, bool RELU_IN, bool BIAS>
__global__ void k_selfloop(const float* __restrict__ h, const float* __restrict__ dis,
                           const float* __restrict__ b, float* __restrict__ agg, int n) {
    int t = blockIdx.x * BLK + threadIdx.x;
    int node = t / C, c = t % C;
    if (node >= n) return;
    float w = dis[node];
    float v = h[t];
    if (RELU_IN) v = fmaxf(v, 0.0f);
    agg[t] = (BIAS ? b[c] : 0.0f) + v * w * w;
}

// agg[dst,C] += (RELU_IN? relu(h):h)[src,C] * dis[src]*dis[dst], one thread per (edge, c)
template <int C, bool RELU_IN>
__global__ void k_scatter(const int* __restrict__ src, const int* __restrict__ dst,
                          const float* __restrict__ h, const float* __restrict__ dis,
                          float* __restrict__ agg, int e) {
    int t = blockIdx.x * BLK + threadIdx.x;
    int edge = t / C, c = t % C;
    if (edge >= e) return;
    int s = src[edge], d = dst[edge];
    float w = dis[s] * dis[d];
    float v = h[(size_t)s * C + c];
    if (RELU_IN) v = fmaxf(v, 0.0f);
    atomicAdd(&agg[(size_t)d * C + c], v * w);
}

__global__ void k_zero(float* __restrict__ out) { out[0] = 0.0f; }

__global__ void k_final(const float* __restrict__ h, const float* __restrict__ Wfc,
                        const float* __restrict__ bfc, float* __restrict__ out, int n,
                        float inv_n) {
    int i = blockIdx.x * BLK + threadIdx.x;
    float v = 0.0f;
    if (i < n) {
        float acc = bfc[0];
        const float* row = h + (size_t)i * 16;
#pragma unroll
        for (int c = 0; c < 16; ++c) acc = fmaf(fmaxf(row[c], 0.0f), Wfc[c], acc);
        v = acc;
    }
#pragma unroll
    for (int off = 32; off > 0; off >>= 1) v += __shfl_down(v, off);
    __shared__ float sw[BLK / 64];
    int wid = threadIdx.x >> 6;
    if ((threadIdx.x & 63) == 0) sw[wid] = v;
    __syncthreads();
    if (threadIdx.x == 0) {
        float t = 0.0f;
#pragma unroll
        for (int w = 0; w < BLK / 64; ++w) t += sw[w];
        atomicAdd(out, t * inv_n);
    }
}

extern "C" void kernel_launch(void* const* d_in, const int* in_sizes, int n_in,
                              void* d_out, int out_size, void* d_ws, size_t ws_size,
                              hipStream_t stream) {
    const float* x   = (const float*)d_in[0];
    const int* ei    = (const int*)d_in[1];   // harness delivers integer inputs as int32
    const float* W1  = (const float*)d_in[2];
    const float* b1  = (const float*)d_in[3];
    const float* W2  = (const float*)d_in[4];
    const float* b2  = (const float*)d_in[5];
    const float* W3  = (const float*)d_in[6];
    const float* b3  = (const float*)d_in[7];
    const float* Wfc = (const float*)d_in[8];
    const float* bfc = (const float*)d_in[9];
    float* out = (float*)d_out;

    const int n = in_sizes[0] / 32;
    const int e = in_sizes[1] / 2;
    const int* src = ei;
    const int* dst = ei + e;

    // ws layout: dis [n, padded], A [n*32], B [n*32]  (~26 MB)
    float* dis = (float*)d_ws;
    float* A = dis + (((size_t)n + 255) & ~(size_t)255);
    float* B = A + (size_t)n * 32;

    auto g1 = [](int work) { return dim3((unsigned)((work + BLK - 1) / BLK)); };

    // degrees -> dis = rsqrt(deg)
    k_deg_init<<<g1(n), BLK, 0, stream>>>(dis, n);
    k_deg_count<<<g1(e), BLK, 0, stream>>>(dst, dis, e);
    k_deg_rsqrt<<<g1(n), BLK, 0, stream>>>(dis, n);

    // L1: 32->16, transform first (16-ch scatter)
    k_transform<32, 16, false, false, false><<<g1(n * 16), BLK, 0, stream>>>(x, W1, nullptr, A, n);
    k_selfloop<16, false, true><<<g1(n * 16), BLK, 0, stream>>>(A, dis, b1, B, n);
    k_scatter<16, false><<<g1(e * 16), BLK, 0, stream>>>(src, dst, A, dis, B, e);
    // h1 = relu(B), applied on subsequent loads

    // L2: 16->32, aggregate first (linearity of scatter), then transform w/ bias+relu
    k_selfloop<16, true, false><<<g1(n * 16), BLK, 0, stream>>>(B, dis, nullptr, A, n);
    k_scatter<16, true><<<g1(e * 16), BLK, 0, stream>>>(src, dst, B, dis, A, e);
    k_transform<16, 32, false, true, true><<<g1(n * 32), BLK, 0, stream>>>(A, W2, b2, B, n);
    // B = relu(h2)

    // L3: 32->16, transform first
    k_transform<32, 16, false, false, false><<<g1(n * 16), BLK, 0, stream>>>(B, W3, nullptr, A, n);
    k_selfloop<16, false, true><<<g1(n * 16), BLK, 0, stream>>>(A, dis, b3, B, n);
    k_scatter<16, false><<<g1(e * 16), BLK, 0, stream>>>(src, dst, A, dis, B, e);

    // out = mean(relu(B) @ Wfc + bfc)
    k_zero<<<1, 1, 0, stream>>>(out);
    k_final<<<g1(n), BLK, 0, stream>>>(B, Wfc, bfc, out, n, 1.0f / (float)n);
}

// Round 3
// 551.478 us; speedup vs baseline: 1.3403x; 1.3403x over previous
//
#include <hip/hip_runtime.h>

static constexpr int BLK = 256;

struct __align__(8) Edge { int s; float w; };

// ---------------- common small kernels ----------------

__global__ void k_deg_count_i(const int* __restrict__ dst, int* __restrict__ deg, int e) {
    int i = blockIdx.x * BLK + threadIdx.x;
    if (i < e) atomicAdd(&deg[dst[i]], 1);
}

__global__ void k_dis_from_ideg(const int* __restrict__ deg, float* __restrict__ dis, int n) {
    int i = blockIdx.x * BLK + threadIdx.x;
    if (i < n) dis[i] = rsqrtf(1.0f + (float)deg[i]);  // +1 self-loop
}

// out[n,COUT] = (RELU_IN? relu(in):in)[n,CIN] @ W[CIN,COUT]  (+b) (+relu)
template <int CIN, int COUT, bool RELU_IN, bool BIAS, bool RELU_OUT>
__global__ void k_transform(const float* __restrict__ in, const float* __restrict__ W,
                            const float* __restrict__ b, float* __restrict__ out, int n) {
    int t = blockIdx.x * BLK + threadIdx.x;
    int node = t / COUT, c = t % COUT;
    if (node >= n) return;
    const float* row = in + (size_t)node * CIN;
    float acc = BIAS ? b[c] : 0.0f;
#pragma unroll
    for (int k = 0; k < CIN; ++k) {
        float v = row[k];
        if (RELU_IN) v = fmaxf(v, 0.0f);
        acc = fmaf(v, W[k * COUT + c], acc);
    }
    if (RELU_OUT) acc = fmaxf(acc, 0.0f);
    out[t] = acc;
}

__global__ void k_zero(float* __restrict__ out) { out[0] = 0.0f; }

__global__ void k_final(const float* __restrict__ h, const float* __restrict__ Wfc,
                        const float* __restrict__ bfc, float* __restrict__ out, int n,
                        float inv_n) {
    int i = blockIdx.x * BLK + threadIdx.x;
    float v = 0.0f;
    if (i < n) {
        float acc = bfc[0];
        const float* row = h + (size_t)i * 16;
#pragma unroll
        for (int c = 0; c < 16; ++c) acc = fmaf(fmaxf(row[c], 0.0f), Wfc[c], acc);
        v = acc;
    }
#pragma unroll
    for (int off = 32; off > 0; off >>= 1) v += __shfl_down(v, off);
    __shared__ float sw[BLK / 64];
    int wid = threadIdx.x >> 6;
    if ((threadIdx.x & 63) == 0) sw[wid] = v;
    __syncthreads();
    if (threadIdx.x == 0) {
        float t = 0.0f;
#pragma unroll
        for (int w = 0; w < BLK / 64; ++w) t += sw[w];
        atomicAdd(out, t * inv_n);
    }
}

// ---------------- CSR build ----------------

// block-level inclusive scan -> exclusive per-element + block total
__global__ void k_scan1(const int* __restrict__ in, int* __restrict__ excl,
                        int* __restrict__ partials, int n) {
    __shared__ int s[BLK];
    int i = blockIdx.x * BLK + threadIdx.x;
    int v = (i < n) ? in[i] : 0;
    s[threadIdx.x] = v;
    __syncthreads();
    for (int off = 1; off < BLK; off <<= 1) {
        int t = (threadIdx.x >= (unsigned)off) ? s[threadIdx.x - off] : 0;
        __syncthreads();
        s[threadIdx.x] += t;
        __syncthreads();
    }
    if (i < n) excl[i] = s[threadIdx.x] - v;
    if (threadIdx.x == BLK - 1) partials[blockIdx.x] = s[BLK - 1];
}

// exclusive scan of P (<=1024) partials, in place
__global__ void k_scan2(int* __restrict__ partials, int P) {
    __shared__ int s[1024];
    int v = ((int)threadIdx.x < P) ? partials[threadIdx.x] : 0;
    s[threadIdx.x] = v;
    __syncthreads();
    for (int off = 1; off < 1024; off <<= 1) {
        int t = (threadIdx.x >= (unsigned)off) ? s[threadIdx.x - off] : 0;
        __syncthreads();
        s[threadIdx.x] += t;
        __syncthreads();
    }
    if ((int)threadIdx.x < P) partials[threadIdx.x] = s[threadIdx.x] - v;
}

__global__ void k_scan3(int* __restrict__ excl, const int* __restrict__ partials, int n) {
    int i = blockIdx.x * BLK + threadIdx.x;
    if (i < n) excl[i] += partials[blockIdx.x];
}

// counting-sort fill: csr[pos] = {src, dis[s]*dis[d]}; cur[d] advances to segment end
__global__ void k_fill(const int* __restrict__ src, const int* __restrict__ dst,
                       const float* __restrict__ dis, int* __restrict__ cur,
                       Edge* __restrict__ csr, int e) {
    int i = blockIdx.x * BLK + threadIdx.x;
    if (i >= e) return;
    int s = src[i], d = dst[i];
    int pos = atomicAdd(&cur[d], 1);
    Edge eg;
    eg.s = s;
    eg.w = dis[s] * dis[d];
    csr[pos] = eg;
}

// gather-aggregate: agg[d,c] = (BIAS?b:0) + relu?(h[d,c])*dis[d]^2 + sum_in relu?(h[s,c])*w
template <bool RELU_IN, bool BIAS>
__global__ void k_agg16(const float* __restrict__ h, const float* __restrict__ dis,
                        const float* __restrict__ b, const int* __restrict__ endp,
                        const int* __restrict__ cnt, const Edge* __restrict__ csr,
                        float* __restrict__ agg, int n) {
    int t = blockIdx.x * BLK + threadIdx.x;
    int d = t >> 4, c = t & 15;
    if (d >= n) return;
    float sd = dis[d];
    float v = h[t];
    if (RELU_IN) v = fmaxf(v, 0.0f);
    float acc0 = (BIAS ? b[c] : 0.0f) + v * sd * sd;
    float acc1 = 0.0f;
    int end = endp[d];
    int k = end - cnt[d];
    for (; k + 1 < end; k += 2) {
        Edge e0 = csr[k], e1 = csr[k + 1];
        float u0 = h[((size_t)e0.s << 4) + c];
        float u1 = h[((size_t)e1.s << 4) + c];
        if (RELU_IN) { u0 = fmaxf(u0, 0.0f); u1 = fmaxf(u1, 0.0f); }
        acc0 = fmaf(u0, e0.w, acc0);
        acc1 = fmaf(u1, e1.w, acc1);
    }
    if (k < end) {
        Edge e0 = csr[k];
        float u0 = h[((size_t)e0.s << 4) + c];
        if (RELU_IN) u0 = fmaxf(u0, 0.0f);
        acc0 = fmaf(u0, e0.w, acc0);
    }
    agg[t] = acc0 + acc1;
}

// ---------------- fallback (atomic scatter) kernels ----------------

__global__ void k_deg_init(float* __restrict__ deg, int n) {
    int i = blockIdx.x * BLK + threadIdx.x;
    if (i < n) deg[i] = 1.0f;
}
__global__ void k_deg_count(const int* __restrict__ dst, float* __restrict__ deg, int e) {
    int i = blockIdx.x * BLK + threadIdx.x;
    if (i < e) atomicAdd(&deg[dst[i]], 1.0f);
}
__global__ void k_deg_rsqrt(float* __restrict__ deg, int n) {
    int i = blockIdx.x * BLK + threadIdx.x;
    if (i < n) deg[i] = rsqrtf(deg[i]);
}
template <int C, bool RELU_IN, bool BIAS>
__global__ void k_selfloop(const float* __restrict__ h, const float* __restrict__ dis,
                           const float* __restrict__ b, float* __restrict__ agg, int n) {
    int t = blockIdx.x * BLK + threadIdx.x;
    int node = t / C, c = t % C;
    if (node >= n) return;
    float w = dis[node];
    float v = h[t];
    if (RELU_IN) v = fmaxf(v, 0.0f);
    agg[t] = (BIAS ? b[c] : 0.0f) + v * w * w;
}
template <int C, bool RELU_IN>
__global__ void k_scatter(const int* __restrict__ src, const int* __restrict__ dst,
                          const float* __restrict__ h, const float* __restrict__ dis,
                          float* __restrict__ agg, int e) {
    int t = blockIdx.x * BLK + threadIdx.x;
    int edge = t / C, c = t % C;
    if (edge >= e) return;
    int s = src[edge], d = dst[edge];
    float w = dis[s] * dis[d];
    float v = h[(size_t)s * C + c];
    if (RELU_IN) v = fmaxf(v, 0.0f);
    atomicAdd(&agg[(size_t)d * C + c], v * w);
}

// ---------------- launch ----------------

extern "C" void kernel_launch(void* const* d_in, const int* in_sizes, int n_in,
                              void* d_out, int out_size, void* d_ws, size_t ws_size,
                              hipStream_t stream) {
    const float* x   = (const float*)d_in[0];
    const int* ei    = (const int*)d_in[1];   // integer inputs delivered as int32
    const float* W1  = (const float*)d_in[2];
    const float* b1  = (const float*)d_in[3];
    const float* W2  = (const float*)d_in[4];
    const float* b2  = (const float*)d_in[5];
    const float* W3  = (const float*)d_in[6];
    const float* b3  = (const float*)d_in[7];
    const float* Wfc = (const float*)d_in[8];
    const float* bfc = (const float*)d_in[9];
    float* out = (float*)d_out;

    const int n = in_sizes[0] / 32;
    const int e = in_sizes[1] / 2;
    const int* src = ei;
    const int* dst = ei + e;

    auto g1 = [](long long work) { return dim3((unsigned)((work + BLK - 1) / BLK)); };
    const int P = (n + BLK - 1) / BLK;  // scan blocks (391 for n=100k, must be <=1024)

    // CSR-path ws layout (256B-aligned chunks)
    auto align_up = [](size_t v) { return (v + 255) & ~(size_t)255; };
    size_t off = 0;
    auto carve = [&](size_t bytes) { size_t o = off; off += align_up(bytes); return o; };
    char* base = (char*)d_ws;
    size_t o_deg  = carve((size_t)n * 4);
    size_t o_cur  = carve((size_t)n * 4);
    size_t o_dis  = carve((size_t)n * 4);
    size_t o_part = carve(1024 * 4);
    size_t o_A    = carve((size_t)n * 32 * 4);
    size_t o_B    = carve((size_t)n * 32 * 4);
    size_t o_csr  = carve((size_t)e * sizeof(Edge));
    bool csr_ok = (off <= ws_size) && (P <= 1024);

    if (csr_ok) {
        int*   deg  = (int*)(base + o_deg);
        int*   cur  = (int*)(base + o_cur);
        float* dis  = (float*)(base + o_dis);
        int*   part = (int*)(base + o_part);
        float* A    = (float*)(base + o_A);
        float* B    = (float*)(base + o_B);
        Edge*  csr  = (Edge*)(base + o_csr);

        // degrees (int) -> dis
        hipMemsetAsync(deg, 0, (size_t)n * 4, stream);
        k_deg_count_i<<<g1(e), BLK, 0, stream>>>(dst, deg, e);
        k_dis_from_ideg<<<g1(n), BLK, 0, stream>>>(deg, dis, n);

        // exclusive scan of deg -> cur (= segment starts)
        k_scan1<<<g1(n), BLK, 0, stream>>>(deg, cur, part, n);
        k_scan2<<<1, 1024, 0, stream>>>(part, P);
        k_scan3<<<g1(n), BLK, 0, stream>>>(cur, part, n);

        // counting-sort edges by dst; cur[d] ends at segment end
        k_fill<<<g1(e), BLK, 0, stream>>>(src, dst, dis, cur, csr, e);

        // L1: transform 32->16 first, then aggregate (bias fused)
        k_transform<32, 16, false, false, false><<<g1((long long)n * 16), BLK, 0, stream>>>(x, W1, nullptr, A, n);
        k_agg16<false, true><<<g1((long long)n * 16), BLK, 0, stream>>>(A, dis, b1, cur, deg, csr, B, n);
        // h1 = relu(B) applied on load

        // L2: aggregate relu(h1) first (scatter linearity), then transform 16->32 (+b2, relu)
        k_agg16<true, false><<<g1((long long)n * 16), BLK, 0, stream>>>(B, dis, nullptr, cur, deg, csr, A, n);
        k_transform<16, 32, false, true, true><<<g1((long long)n * 32), BLK, 0, stream>>>(A, W2, b2, B, n);

        // L3: transform 32->16 first, then aggregate (bias fused)
        k_transform<32, 16, false, false, false><<<g1((long long)n * 16), BLK, 0, stream>>>(B, W3, nullptr, A, n);
        k_agg16<false, true><<<g1((long long)n * 16), BLK, 0, stream>>>(A, dis, b3, cur, deg, csr, B, n);

        k_zero<<<1, 1, 0, stream>>>(out);
        k_final<<<g1(n), BLK, 0, stream>>>(B, Wfc, bfc, out, n, 1.0f / (float)n);
    } else {
        // fallback: atomic scatter path (round-2 layout, ~26MB)
        float* dis = (float*)d_ws;
        float* A = dis + (((size_t)n + 255) & ~(size_t)255);
        float* B = A + (size_t)n * 32;

        k_deg_init<<<g1(n), BLK, 0, stream>>>(dis, n);
        k_deg_count<<<g1(e), BLK, 0, stream>>>(dst, dis, e);
        k_deg_rsqrt<<<g1(n), BLK, 0, stream>>>(dis, n);

        k_transform<32, 16, false, false, false><<<g1((long long)n * 16), BLK, 0, stream>>>(x, W1, nullptr, A, n);
        k_selfloop<16, false, true><<<g1((long long)n * 16), BLK, 0, stream>>>(A, dis, b1, B, n);
        k_scatter<16, false><<<g1((long long)e * 16), BLK, 0, stream>>>(src, dst, A, dis, B, e);

        k_selfloop<16, true, false><<<g1((long long)n * 16), BLK, 0, stream>>>(B, dis, nullptr, A, n);
        k_scatter<16, true><<<g1((long long)e * 16), BLK, 0, stream>>>(src, dst, B, dis, A, e);
        k_transform<16, 32, false, true, true><<<g1((long long)n * 32), BLK, 0, stream>>>(A, W2, b2, B, n);

        k_transform<32, 16, false, false, false><<<g1((long long)n * 16), BLK, 0, stream>>>(B, W3, nullptr, A, n);
        k_selfloop<16, false, true><<<g1((long long)n * 16), BLK, 0, stream>>>(A, dis, b3, B, n);
        k_scatter<16, false><<<g1((long long)e * 16), BLK, 0, stream>>>(src, dst, A, dis, B, e);

        k_zero<<<1, 1, 0, stream>>>(out);
        k_final<<<g1(n), BLK, 0, stream>>>(B, Wfc, bfc, out, n, 1.0f / (float)n);
    }
}